// Round 1
// baseline (458.258 us; speedup 1.0000x reference)
//
#include <hip/hip_runtime.h>
#include <hip/hip_bf16.h>

typedef unsigned short u16;
typedef __attribute__((ext_vector_type(8))) __bf16 bf16x8;
typedef __attribute__((ext_vector_type(4))) float f32x4;
typedef __attribute__((ext_vector_type(8))) unsigned short u16x8;
typedef __attribute__((ext_vector_type(4))) unsigned int u32x4;

static __device__ __forceinline__ u16 f2bf(float x) {
  __hip_bfloat16 h = __float2bfloat16(x);
  u16 u;
  __builtin_memcpy(&u, &h, 2);
  return u;
}

static __device__ __forceinline__ float fast_tanh(float x) {
  // tanh(x) = 1 - 2/(e^{2x}+1); |x| <= ~10 in this problem, no overflow risk.
  float e = __expf(2.0f * x);
  return 1.0f - 2.0f * __builtin_amdgcn_rcpf(e + 1.0f);
}

// XOR swizzle for [R][64]bf16 (128B rows): avoids 16-way bank conflicts on
// ds_read_b128 column accesses (guide §6 G4). Apply to BOTH write and read.
static __device__ __forceinline__ int swz(int row, int byte_in_row) {
  return row * 128 + (byte_in_row ^ ((row & 7) << 4));
}

// ---------------------------------------------------------------------------
// Transpose + cast: out[n][k] (bf16) = in[k][n] (f32).  grid = N blocks.
// ---------------------------------------------------------------------------
__global__ __launch_bounds__(256) void transpose_cast_kernel(
    const float* __restrict__ in, u16* __restrict__ out, int K, int N) {
  int n = blockIdx.x;
  for (int k = threadIdx.x; k < K; k += 256) {
    out[(size_t)n * K + k] = f2bf(in[(size_t)k * N + n]);
  }
}

// ---------------------------------------------------------------------------
// Linear: out[M][640] = A[M][512] @ W[512][640] + bias (W given transposed,
// bf16 [640][512]).  64x64 tile, BK=64, 4 waves.  grid.x = (M/64)*10.
// ---------------------------------------------------------------------------
__global__ __launch_bounds__(256) void linear_kernel(
    const float* __restrict__ A, const u16* __restrict__ Wt,
    const float* __restrict__ bias, float* __restrict__ out) {
  __shared__ u16 sA[64 * 64];
  __shared__ u16 sB[64 * 64];
  const int t = threadIdx.x;
  const int bx = blockIdx.x;
  const int m0 = (bx / 10) * 64;
  const int n0 = (bx % 10) * 64;
  const int lane = t & 63, wid = t >> 6;
  const int wr = wid >> 1, wc = wid & 1;
  const int l15 = lane & 15, lk8 = (lane >> 4) << 3;

  const int srow = t >> 2;      // staging row 0..63
  const int kc = (t & 3) << 4;  // element offset 0,16,32,48

  f32x4 acc[2][2] = {};

  for (int k0 = 0; k0 < 512; k0 += 64) {
    {  // stage A: f32 -> bf16
      const float4* gp = (const float4*)(A + (size_t)(m0 + srow) * 512 + k0 + kc);
      u16 tmp[16];
#pragma unroll
      for (int i = 0; i < 4; ++i) {
        float4 v = gp[i];
        tmp[i * 4 + 0] = f2bf(v.x);
        tmp[i * 4 + 1] = f2bf(v.y);
        tmp[i * 4 + 2] = f2bf(v.z);
        tmp[i * 4 + 3] = f2bf(v.w);
      }
      *(u16x8*)((char*)sA + swz(srow, kc * 2)) = *(u16x8*)&tmp[0];
      *(u16x8*)((char*)sA + swz(srow, kc * 2 + 16)) = *(u16x8*)&tmp[8];
    }
    {  // stage B: copy bf16 (pre-transposed)
      const int off = (t & 3) << 5;  // 0,32,64,96 bytes
      const char* gsrc = (const char*)Wt + ((size_t)(n0 + srow) * 512 + k0) * 2 + off;
      u32x4 q0 = *(const u32x4*)gsrc;
      u32x4 q1 = *(const u32x4*)(gsrc + 16);
      *(u32x4*)((char*)sB + swz(srow, off)) = q0;
      *(u32x4*)((char*)sB + swz(srow, off + 16)) = q1;
    }
    __syncthreads();
#pragma unroll
    for (int kh = 0; kh < 2; ++kh) {
      const int kbyte = kh * 64 + lk8 * 2;
      bf16x8 av[2], bv[2];
#pragma unroll
      for (int mf = 0; mf < 2; ++mf)
        av[mf] = *(const bf16x8*)((char*)sA + swz(wr * 32 + mf * 16 + l15, kbyte));
#pragma unroll
      for (int nf = 0; nf < 2; ++nf)
        bv[nf] = *(const bf16x8*)((char*)sB + swz(wc * 32 + nf * 16 + l15, kbyte));
#pragma unroll
      for (int mf = 0; mf < 2; ++mf)
#pragma unroll
        for (int nf = 0; nf < 2; ++nf)
          acc[mf][nf] = __builtin_amdgcn_mfma_f32_16x16x32_bf16(
              av[mf], bv[nf], acc[mf][nf], 0, 0, 0);
    }
    __syncthreads();
  }

  const int r4 = (lane >> 4) << 2;
#pragma unroll
  for (int nf = 0; nf < 2; ++nf) {
    const int nc = n0 + wc * 32 + nf * 16 + l15;
    const float bjv = bias[nc];
#pragma unroll
    for (int mf = 0; mf < 2; ++mf) {
      const int mr = m0 + wr * 32 + mf * 16 + r4;
#pragma unroll
      for (int r = 0; r < 4; ++r)
        out[(size_t)(mr + r) * 640 + nc] = acc[mf][nf][r] + bjv;
    }
  }
}

// ---------------------------------------------------------------------------
// Fused joint: out[bt][u][v] = tanh(f[bt][:] + g[b][u][:]) @ Wj[:, v] + b_joint
// grid = (B*T, V/256), 512 threads (8 waves, 2x4), tile 128(U) x 256(V), BK=64
// ---------------------------------------------------------------------------
__global__ __launch_bounds__(512) void fused_joint_kernel(
    const float* __restrict__ f,   // [1024][640]
    const float* __restrict__ g,   // [4][128][640]
    const u16* __restrict__ Wjt,   // [1024][640] bf16 (W_joint^T)
    const float* __restrict__ bj,  // [1024]
    float* __restrict__ out) {     // [1024][128][1024]
  __shared__ u16 sA[128 * 64];  // 16 KiB
  __shared__ u16 sB[256 * 64];  // 32 KiB
  const int t = threadIdx.x;
  const int bt = blockIdx.x;
  const int b = bt >> 8;
  const int v0 = blockIdx.y << 8;
  const float* frow = f + (size_t)bt * 640;
  const float* gbase = g + (size_t)b * 128 * 640;

  const int lane = t & 63, wid = t >> 6;
  const int wr = wid >> 2, wc = wid & 3;
  const int l15 = lane & 15, lk8 = (lane >> 4) << 3;

  const int au = t >> 2;         // A-stage row (u) 0..127
  const int akc = (t & 3) << 4;  // element offset 0,16,32,48
  const int bn = t >> 1;         // B-stage row (n) 0..255
  const int boff = (t & 1) << 6; // byte offset 0 or 64

  f32x4 acc[4][4] = {};

  for (int k0 = 0; k0 < 640; k0 += 64) {
    {  // stage A: tanh(f + g) -> bf16 (swizzled)
      const float4* gp = (const float4*)(gbase + (size_t)au * 640 + k0 + akc);
      const float4* fp = (const float4*)(frow + k0 + akc);
      u16 tmp[16];
#pragma unroll
      for (int i = 0; i < 4; ++i) {
        float4 gv = gp[i];
        float4 fv = fp[i];
        tmp[i * 4 + 0] = f2bf(fast_tanh(gv.x + fv.x));
        tmp[i * 4 + 1] = f2bf(fast_tanh(gv.y + fv.y));
        tmp[i * 4 + 2] = f2bf(fast_tanh(gv.z + fv.z));
        tmp[i * 4 + 3] = f2bf(fast_tanh(gv.w + fv.w));
      }
      *(u16x8*)((char*)sA + swz(au, akc * 2)) = *(u16x8*)&tmp[0];
      *(u16x8*)((char*)sA + swz(au, akc * 2 + 16)) = *(u16x8*)&tmp[8];
    }
    {  // stage B: copy W_joint^T slice (bf16, L2-resident)
      const char* gsrc = (const char*)Wjt + ((size_t)(v0 + bn) * 640 + k0) * 2 + boff;
#pragma unroll
      for (int i = 0; i < 4; ++i) {
        u32x4 q = *(const u32x4*)(gsrc + i * 16);
        *(u32x4*)((char*)sB + swz(bn, boff + i * 16)) = q;
      }
    }
    __syncthreads();
#pragma unroll
    for (int kh = 0; kh < 2; ++kh) {
      const int kbyte = kh * 64 + lk8 * 2;
      bf16x8 av[4], bv[4];
#pragma unroll
      for (int mf = 0; mf < 4; ++mf)
        av[mf] = *(const bf16x8*)((char*)sA + swz(wr * 64 + mf * 16 + l15, kbyte));
#pragma unroll
      for (int nf = 0; nf < 4; ++nf)
        bv[nf] = *(const bf16x8*)((char*)sB + swz(wc * 64 + nf * 16 + l15, kbyte));
#pragma unroll
      for (int mf = 0; mf < 4; ++mf)
#pragma unroll
        for (int nf = 0; nf < 4; ++nf)
          acc[mf][nf] = __builtin_amdgcn_mfma_f32_16x16x32_bf16(
              av[mf], bv[nf], acc[mf][nf], 0, 0, 0);
    }
    __syncthreads();
  }

  const int r4 = (lane >> 4) << 2;
#pragma unroll
  for (int nf = 0; nf < 4; ++nf) {
    const int v = v0 + wc * 64 + nf * 16 + l15;
    const float bjv = bj[v];
#pragma unroll
    for (int mf = 0; mf < 4; ++mf) {
      const int u = wr * 64 + mf * 16 + r4;
      const size_t o = ((size_t)bt * 128 + u) * 1024 + v;
#pragma unroll
      for (int r = 0; r < 4; ++r)
        out[o + (size_t)r * 1024] = acc[mf][nf][r] + bjv;
    }
  }
}

extern "C" void kernel_launch(void* const* d_in, const int* in_sizes, int n_in,
                              void* d_out, int out_size, void* d_ws, size_t ws_size,
                              hipStream_t stream) {
  const float* enc = (const float*)d_in[0];     // [4][256][512]
  const float* pred = (const float*)d_in[1];    // [4][128][512]
  const float* W_enc = (const float*)d_in[2];   // [512][640]
  const float* b_enc = (const float*)d_in[3];   // [640]
  const float* W_pred = (const float*)d_in[4];  // [512][640]
  const float* b_pred = (const float*)d_in[5];  // [640]
  const float* W_joint = (const float*)d_in[6]; // [640][1024]
  const float* b_joint = (const float*)d_in[7]; // [1024]
  float* out = (float*)d_out;

  char* ws = (char*)d_ws;
  float* f = (float*)ws;                               // 1024*640*4  = 2621440 B
  float* gbuf = (float*)(ws + 2621440);                // 512*640*4   = 1310720 B
  u16* Wet = (u16*)(ws + 2621440 + 1310720);           // 640*512*2   = 655360 B
  u16* Wpt = (u16*)(ws + 2621440 + 1310720 + 655360);  // 640*512*2   = 655360 B
  u16* Wjt = (u16*)(ws + 2621440 + 1310720 + 2 * 655360);  // 1024*640*2 = 1310720 B

  // 1) transpose+cast the three weight matrices to bf16 [N][K]
  transpose_cast_kernel<<<640, 256, 0, stream>>>(W_enc, Wet, 512, 640);
  transpose_cast_kernel<<<640, 256, 0, stream>>>(W_pred, Wpt, 512, 640);
  transpose_cast_kernel<<<1024, 256, 0, stream>>>(W_joint, Wjt, 640, 1024);

  // 2) f = enc @ W_enc + b_enc   (M = 1024);  g = pred @ W_pred + b_pred (M = 512)
  linear_kernel<<<16 * 10, 256, 0, stream>>>(enc, Wet, b_enc, f);
  linear_kernel<<<8 * 10, 256, 0, stream>>>(pred, Wpt, b_pred, gbuf);

  // 3) fused tanh-broadcast + joint projection
  fused_joint_kernel<<<dim3(1024, 4), 512, 0, stream>>>(f, gbuf, Wjt, b_joint, out);
}